// Round 15
// baseline (825.762 us; speedup 1.0000x reference)
//
#include <hip/hip_runtime.h>
#include <math.h>

#define TT 36
#define NP 160
#define KDIM 641
#define PP 512
#define NU 321            // pair-units: u=0 const col; 1..160 cos; 161..320 sin
#define NSLOT 384         // padded unit slots (321..383 stay zero)
#define BT 512            // 8 waves
#define NW 8
#define LAM 0.1f
#define EPSW 0.01f
#define NITER 200
#define NPOW 160

// ---------------- dictionary ----------------
__global__ void k_build_dic(const float* __restrict__ rr, const float* __restrict__ th,
                            float* __restrict__ D, float* __restrict__ outD) {
  int idx = blockIdx.x * blockDim.x + threadIdx.x;
  if (idx >= TT * KDIM) return;
  int t = idx / KDIM, k = idx % KDIM;
  float v;
  if (k == 0) {
    v = 1.0f;
  } else {
    int g = (k - 1) / NP;     // 0:p*cos 1:m*cos 2:p*sin 3:m*sin
    int p = (k - 1) % NP;
    float ft = (float)t;
    float pw = powf(rr[p], ft);
    if ((g == 1 || g == 3) && (t & 1)) pw = -pw;
    float ang = ft * th[p];
    v = pw * ((g < 2) ? cosf(ang) : sinf(ang));
  }
  D[idx] = v;
  outD[idx] = v;
}

// ---------------- G = D D^T (36x36) ----------------
__global__ void k_G(const float* __restrict__ D, float* __restrict__ G) {
  int idx = blockIdx.x * blockDim.x + threadIdx.x;
  if (idx >= TT * TT) return;
  int i = idx / TT, j = idx % TT;
  float s = 0.0f;
  for (int k = 0; k < KDIM; ++k) s = fmaf(D[i * KDIM + k], D[j * KDIM + k], s);
  G[idx] = s;
}

// ---------------- power iteration on 36x36 (one wave): L, mu table; reset sync slots ----------------
__global__ void k_power(const float* __restrict__ G, float* __restrict__ Lb,
                        float* __restrict__ mug) {
  int lane = threadIdx.x;   // blockDim = 64
  float g[TT];
#pragma unroll
  for (int j = 0; j < TT; ++j) g[j] = (lane < TT) ? G[lane * TT + j] : 0.0f;
  float v = (lane < TT) ? 1.0f : 0.0f;
  for (int it = 0; it < NPOW; ++it) {
    float u = 0.0f;
#pragma unroll
    for (int j = 0; j < TT; ++j) u = fmaf(g[j], __shfl(v, j, 64), u);
    float s = u * u;
#pragma unroll
    for (int o = 32; o >= 1; o >>= 1) s += __shfl_xor(s, o, 64);
    v = u * rsqrtf(s);
  }
  float u = 0.0f;
#pragma unroll
  for (int j = 0; j < TT; ++j) u = fmaf(g[j], __shfl(v, j, 64), u);
  float num = v * u, den = v * v;
#pragma unroll
  for (int o = 32; o >= 1; o >>= 1) {
    num += __shfl_xor(num, o, 64);
    den += __shfl_xor(den, o, 64);
  }
  if (lane == 0) {
    float L = num / den;   // Rayleigh quotient = lambda_max
    Lb[0] = L;
    Lb[1] = 1.0f / L;
    Lb[3] = 0.0f;          // norm accumulator round 0 (re-zeroed every launch: replay-safe)
    Lb[4] = 0.0f;          // norm accumulator round 1
    ((unsigned*)(Lb + 8))[0] = 0u;   // barrier counter round 0
    ((unsigned*)(Lb + 8))[1] = 0u;   // barrier counter round 1
    float t = 1.0f;
    for (int i = 0; i < NITER; ++i) {
      float tn = 0.5f * (1.0f + sqrtf(1.0f + 4.0f * t * t));
      mug[i] = (t - 1.0f) / tn;
      t = tn;
    }
  }
}

// ---- DPP wave-64 sum; total valid in lane 63 ----
template <int C>
__device__ __forceinline__ float dppadd(float v) {
  int t = __builtin_amdgcn_update_dpp(0, __float_as_int(v), C, 0xf, 0xf, true);
  return v + __int_as_float(t);
}
__device__ __forceinline__ float wave_sum63(float v) {
  v = dppadd<0xB1>(v);    // quad_perm [1,0,3,2]
  v = dppadd<0x4E>(v);    // quad_perm [2,3,0,1]
  v = dppadd<0x141>(v);   // row_half_mirror
  v = dppadd<0x140>(v);   // row_mirror
  v = dppadd<0x142>(v);   // row_bcast15
  v = dppadd<0x143>(v);   // row_bcast31
  return v;               // lane 63 holds the total
}

// plus-group column index of pair-unit u (u < NU)
__device__ __forceinline__ int colmap(int u) {
  return (u == 0) ? 0 : ((u < 161) ? u : u + 160);
}

// ---------------- fused 3-round FISTA: one column per block, 8 waves, software grid barrier ----------------
// Grid = 512 = 2 blocks/CU exactly; __launch_bounds__(512,4) pins resources so both fit
// (r11 measured both resident). All blocks reach the barrier before any exits -> no deadlock;
// spin failsafe guarantees termination regardless.
__global__ __launch_bounds__(BT, 4) void k_fused(
    const float* __restrict__ Dg, const float* __restrict__ X,
    float* __restrict__ Lb, const float* __restrict__ mug,
    float* __restrict__ out) {
  __shared__ __align__(16) float2 ylds2[NSLOT];   // slot u = (yP_u, yM_u); 321..383 stay (0,0)
  __shared__ float pbuf[NW * NSLOT];              // per-wave phase-2 partials (disjoint)
  __shared__ float muLDS[NITER];
  __shared__ float rn[NW];
  __shared__ float nrmsh;

  const int tid  = threadIdx.x;
  const int lane = tid & 63;
  const int w    = tid >> 6;          // wave 0..7; rows t = w + 8i (parity = w&1)
  const float sgn = (w & 1) ? -1.0f : 1.0f;
  const int p    = blockIdx.x;        // column

  const float Linv = Lb[1];
  const float sqL  = sqrtf(Linv);
  const float lamL = LAM * Linv;

  // ---- unit ownership: one per thread, tid < NU
  const bool act = (tid < NU);
  const int u    = act ? tid : 0;
  const int kP   = colmap(u);
  const int kM   = (u == 0) ? 0 : kP + 160;

  // ---- Dq[i][j] = sqrt(Linv) * D[w+8i][colmap(lane+64j)]; zero pad rows/units
  float Dq[5][6];
#pragma unroll
  for (int i = 0; i < 5; ++i)
#pragma unroll
    for (int j = 0; j < 6; ++j) {
      const int t = w + 8 * i;
      const int ua = lane + 64 * j;
      Dq[i][j] = (t < TT && ua < NU) ? Dg[t * KDIM + colmap(ua)] * sqL : 0.0f;
    }

  // ---- c0 = Linv*(D^T x_col) via even/odd split — once for all rounds
  float c0P, c0M;
  {
    float sE0 = 0.f, sO0 = 0.f;
#pragma unroll 6
    for (int t = 0; t < TT; ++t) {
      const float dv = act ? Dg[t * KDIM + kP] : 0.0f;
      const float xv = X[t * PP + p];             // block-uniform
      if (t & 1) sO0 = fmaf(dv, xv, sO0);
      else       sE0 = fmaf(dv, xv, sE0);
    }
    c0P = (sE0 + sO0) * Linv;
    c0M = (sE0 - sO0) * Linv;
  }

  if (tid < NITER) muLDS[tid] = mug[tid];

  float xP = 0.f, xM = 0.f, yP = 0.f, yM = 0.f;
  float rninv = 0.f;                              // 1/||wr|| (set after rounds 0,1)

  for (int r = 0; r < 3; ++r) {
    // ---- per-round thresholds (previous round's x is still in registers)
    float wlP, wlM;
    if (r == 0) {
      wlP = lamL; wlM = lamL;
    } else {
      const float nl = lamL * rninv;
      wlP = nl / (fabsf(xP) + EPSW);
      wlM = nl / (fabsf((u > 0) ? xM : xP) + EPSW);
    }
    const float cmP = c0P - wlP, cpP = c0P + wlP;
    const float cmM = c0M - wlM, cpM = c0M + wlM;
    xP = 0.f; xM = 0.f; yP = 0.f; yM = 0.f;
    if (tid < NSLOT) ylds2[tid] = make_float2(0.f, 0.f);
    __syncthreads();

    for (int it = 0; it < NITER; ++it) {
      // ===== phase 1: z rows t=w+8i: acc = sum_units Dq * (yP ± yM) =====
      float acc[5] = {0.f, 0.f, 0.f, 0.f, 0.f};
#pragma unroll
      for (int j = 0; j < 6; ++j) {
        const float2 yv = ylds2[lane + 64 * j];   // ds_read_b64, conflict-free
        const float op = fmaf(sgn, yv.y, yv.x);   // yP ± yM, parity wave-uniform
#pragma unroll
        for (int i = 0; i < 5; ++i) acc[i] = fmaf(Dq[i][j], op, acc[i]);
      }
      float z[5];
#pragma unroll
      for (int i = 0; i < 5; ++i) {
        const float rr_ = wave_sum63(acc[i]);
        z[i] = __int_as_float(__builtin_amdgcn_readlane(__float_as_int(rr_), 63));
      }
      // ===== phase-2 partials: pw[u] = sum_i Dq[i][u]*z[i] (this wave's rows only) =====
#pragma unroll
      for (int j = 0; j < 6; ++j) {
        float pw = Dq[0][j] * z[0];
#pragma unroll
        for (int i = 1; i < 5; ++i) pw = fmaf(Dq[i][j], z[i], pw);
        pbuf[w * NSLOT + lane + 64 * j] = pw;     // disjoint per wave: no contention
      }
      __syncthreads();

      // ===== owner: sum partials by parity, reconstruct pair rows, shrink, momentum =====
      const float mu = muLDS[it];
      if (act) {
        const float sE = (pbuf[0 * NSLOT + u] + pbuf[2 * NSLOT + u])
                       + (pbuf[4 * NSLOT + u] + pbuf[6 * NSLOT + u]);
        const float sO = (pbuf[1 * NSLOT + u] + pbuf[3 * NSLOT + u])
                       + (pbuf[5 * NSLOT + u] + pbuf[7 * NSLOT + u]);
        const float sP = sE + sO, sM = sE - sO;   // = Linv*(DtD y) rows kP,kM
        float uu, xn;
        uu = yP - sP; xn = fmaxf(0.f, uu + cmP) + fminf(0.f, uu + cpP);
        yP = fmaf(mu, xn - xP, xn); xP = xn;
        uu = yM - sM; xn = fmaxf(0.f, uu + cmM) + fminf(0.f, uu + cpM);
        yM = fmaf(mu, xn - xM, xn); xM = xn;
        ylds2[u] = make_float2(yP, (u > 0) ? yM : 0.0f);
      }
      __syncthreads();
    }

    // ---- inter-round: grid-wide ||wr||^2 via software barrier; x stays in registers
    if (r < 2) {
      float s = 0.0f;
      if (act) {
        const float rP = 1.0f / (fabsf(xP) + EPSW);
        s = rP * rP;
        if (u > 0) { const float rM = 1.0f / (fabsf(xM) + EPSW); s += rM * rM; }
      }
      s = wave_sum63(s);
      if (lane == 63) rn[w] = s;
      __syncthreads();
      if (tid == 0) {
        float tot = 0.f;
#pragma unroll
        for (int i = 0; i < NW; ++i) tot += rn[i];
        __hip_atomic_fetch_add(&Lb[3 + r], tot, __ATOMIC_RELEASE, __HIP_MEMORY_SCOPE_AGENT);
        unsigned* cnt = (unsigned*)(Lb + 8) + r;
        __hip_atomic_fetch_add(cnt, 1u, __ATOMIC_ACQ_REL, __HIP_MEMORY_SCOPE_AGENT);
        unsigned spins = 0;
        while (__hip_atomic_load(cnt, __ATOMIC_ACQUIRE, __HIP_MEMORY_SCOPE_AGENT) < (unsigned)PP) {
          if (++spins > 100000000u) break;        // failsafe: never hang
          __builtin_amdgcn_s_sleep(8);
        }
        nrmsh = __hip_atomic_load(&Lb[3 + r], __ATOMIC_RELAXED, __HIP_MEMORY_SCOPE_AGENT);
      }
      __syncthreads();
      rninv = rsqrtf(nrmsh);
    }
  }

  // ---- emit final x straight to out
  if (act) {
    out[kP * PP + p] = xP;
    if (u > 0) out[kM * PP + p] = xM;
  }
}

// ---------------- host ----------------
extern "C" void kernel_launch(void* const* d_in, const int* in_sizes, int n_in,
                              void* d_out, int out_size, void* d_ws, size_t ws_size,
                              hipStream_t stream) {
  const float* x  = (const float*)d_in[0];
  const float* rr = (const float*)d_in[1];
  const float* th = (const float*)d_in[2];
  float* out = (float*)d_out;
  float* ws  = (float*)d_ws;

  size_t off = 0;
  auto alloc = [&](size_t n) {
    float* p = ws + off;
    off += (n + 63) & ~(size_t)63;
    return p;
  };
  float* D    = alloc((size_t)TT * KDIM);
  float* G    = alloc(TT * TT);
  float* Lb   = alloc(16);
  float* mug  = alloc(NITER);
  if (off * sizeof(float) > ws_size) return;

  k_build_dic<<<(TT * KDIM + 255) / 256, 256, 0, stream>>>(rr, th, D, out + (size_t)KDIM * PP);
  k_G<<<(TT * TT + 255) / 256, 256, 0, stream>>>(D, G);
  k_power<<<1, 64, 0, stream>>>(G, Lb, mug);
  k_fused<<<PP, BT, 0, stream>>>(D, x, Lb, mug, out);
}

// Round 16
// 800.928 us; speedup vs baseline: 1.0310x; 1.0310x over previous
//
#include <hip/hip_runtime.h>
#include <math.h>

#define TT 36
#define NP 160
#define KDIM 641
#define PP 512
#define KPAD 704          // transposed-x row stride
#define NU 321            // pair-units: u=0 const col; 1..160 cos; 161..320 sin
#define YSLOTS 384        // float2 slots in ylds2
#define BT 512            // 8 waves
#define LAM 0.1f
#define EPSW 0.01f
#define NITER 200
#define NPOW 160

// ---------------- dictionary ----------------
__global__ void k_build_dic(const float* __restrict__ rr, const float* __restrict__ th,
                            float* __restrict__ D, float* __restrict__ outD) {
  int idx = blockIdx.x * blockDim.x + threadIdx.x;
  if (idx >= TT * KDIM) return;
  int t = idx / KDIM, k = idx % KDIM;
  float v;
  if (k == 0) {
    v = 1.0f;
  } else {
    int g = (k - 1) / NP;     // 0:p*cos 1:m*cos 2:p*sin 3:m*sin
    int p = (k - 1) % NP;
    float ft = (float)t;
    float pw = powf(rr[p], ft);
    if ((g == 1 || g == 3) && (t & 1)) pw = -pw;
    float ang = ft * th[p];
    v = pw * ((g < 2) ? cosf(ang) : sinf(ang));
  }
  D[idx] = v;
  outD[idx] = v;
}

// ---------------- merged prep: G = D D^T (LDS) -> power iteration -> L, mu ----------------
__global__ __launch_bounds__(1024) void k_prep(const float* __restrict__ D,
                                               float* __restrict__ Lb,
                                               float* __restrict__ mug) {
  __shared__ float G[TT * TT];
  const int tid = threadIdx.x;

  // ---- G entries: 1296 dots of length 641 over 1024 threads
  for (int idx = tid; idx < TT * TT; idx += 1024) {
    const int i = idx / TT, j = idx % TT;
    float s = 0.0f;
    for (int k = 0; k < KDIM; ++k) s = fmaf(D[i * KDIM + k], D[j * KDIM + k], s);
    G[idx] = s;
  }
  __syncthreads();

  // ---- wave 0: power iteration on LDS-resident G
  if (tid < 64) {
    const int lane = tid;
    float g[TT];
#pragma unroll
    for (int j = 0; j < TT; ++j) g[j] = (lane < TT) ? G[lane * TT + j] : 0.0f;
    float v = (lane < TT) ? 1.0f : 0.0f;
    for (int it = 0; it < NPOW; ++it) {
      float u = 0.0f;
#pragma unroll
      for (int j = 0; j < TT; ++j) u = fmaf(g[j], __shfl(v, j, 64), u);
      float s = u * u;
#pragma unroll
      for (int o = 32; o >= 1; o >>= 1) s += __shfl_xor(s, o, 64);
      v = u * rsqrtf(s);
    }
    float u = 0.0f;
#pragma unroll
    for (int j = 0; j < TT; ++j) u = fmaf(g[j], __shfl(v, j, 64), u);
    float num = v * u, den = v * v;
#pragma unroll
    for (int o = 32; o >= 1; o >>= 1) {
      num += __shfl_xor(num, o, 64);
      den += __shfl_xor(den, o, 64);
    }
    if (lane == 0) {
      float L = num / den;   // Rayleigh quotient = lambda_max
      Lb[0] = L;
      Lb[1] = 1.0f / L;
      Lb[3] = 0.0f;          // reset norm accumulator (graph-replay safe)
      float t = 1.0f;
      for (int i = 0; i < NITER; ++i) {
        float tn = 0.5f * (1.0f + sqrtf(1.0f + 4.0f * t * t));
        mug[i] = (t - 1.0f) / tn;
        t = tn;
      }
    }
  }
}

// ---- DPP wave-64 sum; total valid in lane 63 ----
template <int C>
__device__ __forceinline__ float dppadd(float v) {
  int t = __builtin_amdgcn_update_dpp(0, __float_as_int(v), C, 0xf, 0xf, true);
  return v + __int_as_float(t);
}
__device__ __forceinline__ float wave_sum63(float v) {
  v = dppadd<0xB1>(v);    // quad_perm [1,0,3,2]
  v = dppadd<0x4E>(v);    // quad_perm [2,3,0,1]
  v = dppadd<0x141>(v);   // row_half_mirror
  v = dppadd<0x140>(v);   // row_mirror
  v = dppadd<0x142>(v);   // row_bcast15
  v = dppadd<0x143>(v);   // row_bcast31
  return v;
}

// plus-group column index of pair-unit u (u < NU)
__device__ __forceinline__ int colmap(int u) {
  return (u == 0) ? 0 : ((u < 161) ? u : u + 160);
}

// ---------------- persistent per-round FISTA: one column per block, 8 waves ----------------
// (verbatim r8 structure — best measured: 211 us/round)
__global__ __attribute__((amdgpu_flat_work_group_size(BT, BT), amdgpu_waves_per_eu(4, 4)))
void k_round(
    const float* __restrict__ Dg, const float* __restrict__ X,
    float* __restrict__ Lb, const float* __restrict__ mug,
    const float* __restrict__ xprev, float* __restrict__ xout,
    int first, int last) {
  __shared__ __align__(16) float2 ylds2[YSLOTS];   // slot u = (yP_u, yM_u)
  __shared__ __align__(16) float zlds[TT];
  __shared__ float muLDS[NITER];

  const int tid  = threadIdx.x;
  const int lane = tid & 63;
  const int w    = tid >> 6;          // wave 0..7
  const int nr   = (w < 4) ? 5 : 4;   // rows owned: t = w + 8i, i < nr
  const float sgn = (w & 1) ? -1.0f : 1.0f;   // row parity uniform per wave
  const int p    = blockIdx.x;        // column

  const float Linv = Lb[1];
  const float lamL = LAM * Linv;

  // ---- phase-2 pair-unit: one per thread (tid < NU)
  const int u = tid;
  const bool act = (u < NU);
  const int kP = colmap(act ? u : 0);
  const int kM = (u == 0 || !act) ? 0 : kP + 160;   // minus-group row (guarded by u>0)

  // ---- phase-1 Dq: rows t = w+8i, plus-column of unit ua = lane + 64j
  float Dq[5][6];
#pragma unroll
  for (int i = 0; i < 5; ++i)
#pragma unroll
    for (int j = 0; j < 6; ++j) {
      const int ua = lane + 64 * j;
      Dq[i][j] = (i < nr && ua < NU) ? Dg[(w + 8 * i) * KDIM + colmap(ua)] : 0.0f;
    }
#pragma unroll
  for (int i = 0; i < 5; ++i)
#pragma unroll
    for (int j = 0; j < 6; ++j)
      asm volatile("v_mov_b32 %0, %0" : "+v"(Dq[i][j]));   // pin: no remat/reload

  // ---- phase-2 D column (plus member) in registers, pinned
  float Dc[TT];
#pragma unroll
  for (int t = 0; t < TT; ++t) Dc[t] = act ? Dg[t * KDIM + kP] : 0.0f;
#pragma unroll
  for (int t = 0; t < TT; ++t)
    asm volatile("v_mov_b32 %0, %0" : "+v"(Dc[t]));        // pin: no remat/reload

  // ---- c0 = Linv * (D^T x_col) via even/odd split; cm/cp thresholds
  float cmP, cpP, cmM, cpM;
  {
    float sE = 0.f, sO = 0.f;
#pragma unroll
    for (int t = 0; t < TT; ++t) {
      const float xv = X[t * PP + p];       // block-uniform: broadcast
      if (t & 1) sO = fmaf(Dc[t], xv, sO);
      else       sE = fmaf(Dc[t], xv, sE);
    }
    const float c0P = (sE + sO) * Linv, c0M = (sE - sO) * Linv;
    float wlP = lamL, wlM = lamL;
    if (!first) {
      const float nl = lamL * Lb[2];        // lam*Linv/||wr||
      wlP = nl / (fabsf(xprev[p * KPAD + kP]) + EPSW);
      wlM = nl / (fabsf(xprev[p * KPAD + ((u > 0) ? kM : kP)]) + EPSW);
    }
    cmP = c0P - wlP; cpP = c0P + wlP;
    cmM = c0M - wlM; cpM = c0M + wlM;
  }

  // ---- stage mu table; zero y pairs (incl. pad slots, read by inactive lanes)
  if (tid < NITER) muLDS[tid] = mug[tid];
  if (tid < YSLOTS) ylds2[tid] = make_float2(0.f, 0.f);

  float xP = 0.f, xM = 0.f, yP = 0.f, yM = 0.f;

  __syncthreads();

  for (int it = 0; it < NITER; ++it) {
    // ===== phase 1: z = Linv * (D @ y), pole-paired; rows t = w + 8i =====
    float acc[5];
#pragma unroll
    for (int i = 0; i < 5; ++i) acc[i] = 0.f;
#pragma unroll
    for (int j = 0; j < 6; ++j) {
      const float2 yv = ylds2[lane + 64 * j];   // ds_read_b64: base + imm offset
      const float op = fmaf(sgn, yv.y, yv.x);   // yP ± yM, parity wave-uniform
#pragma unroll
      for (int i = 0; i < 5; ++i) acc[i] = fmaf(Dq[i][j], op, acc[i]);
    }
#pragma unroll
    for (int i = 0; i < 5; ++i) {
      if (i < nr) {
        const float r = wave_sum63(acc[i]);
        if (lane == 63) zlds[w + 8 * i] = r * Linv;
      }
    }
    __syncthreads();

    // ===== phase 2: both rows of the pair via even/odd sums =====
    const float mu = muLDS[it];
    if (act) {
      float sE = 0.f, sO = 0.f;
#pragma unroll
      for (int q = 0; q < 9; ++q) {
        const float4 z4 = *reinterpret_cast<const float4*>(&zlds[4 * q]);  // broadcast
        sE = fmaf(Dc[4*q+0], z4.x, sE);
        sO = fmaf(Dc[4*q+1], z4.y, sO);
        sE = fmaf(Dc[4*q+2], z4.z, sE);
        sO = fmaf(Dc[4*q+3], z4.w, sO);
      }
      const float sP = sE + sO, sM = sE - sO;
      float uu, xn;
      uu = yP - sP; xn = fmaxf(0.f, uu + cmP) + fminf(0.f, uu + cpP);
      yP = fmaf(mu, xn - xP, xn); xP = xn;
      uu = yM - sM; xn = fmaxf(0.f, uu + cmM) + fminf(0.f, uu + cpM);
      yM = fmaf(mu, xn - xM, xn); xM = xn;
      const float yMs = (u == 0) ? 0.0f : yM;   // unit 0 has no minus-row
      ylds2[u] = make_float2(yP, yMs);          // ds_write_b64
    }
    __syncthreads();
  }

  // ---- emit x
  if (act) {
    if (last) {
      xout[kP * PP + p] = xP;
      if (u > 0) xout[kM * PP + p] = xM;
    } else {
      xout[p * KPAD + kP] = xP;             // transposed for next round's reads
      if (u > 0) xout[p * KPAD + kM] = xM;
    }
  }

  // ---- fused reweight-norm accumulation: sum of wr^2 over this column
  if (!last) {
    float s = 0.0f;
    if (act) {
      const float rP = 1.0f / (fabsf(xP) + EPSW);
      s = rP * rP;
      if (u > 0) { const float rM = 1.0f / (fabsf(xM) + EPSW); s += rM * rM; }
    }
    s = wave_sum63(s);
    if (lane == 63) zlds[w] = s;            // zlds free after the loop
    __syncthreads();
    if (tid == 0) {
      float tot = 0.f;
#pragma unroll
      for (int i = 0; i < 8; ++i) tot += zlds[i];
      atomicAdd(&Lb[3], tot);
    }
  }
}

// ---------------- finalize norm: Lb[2] = 1/||wr||, reset accumulator ----------------
__global__ void k_norm(float* __restrict__ Lb) {
  if (threadIdx.x == 0) {
    Lb[2] = 1.0f / sqrtf(Lb[3]);
    Lb[3] = 0.0f;
  }
}

// ---------------- host ----------------
extern "C" void kernel_launch(void* const* d_in, const int* in_sizes, int n_in,
                              void* d_out, int out_size, void* d_ws, size_t ws_size,
                              hipStream_t stream) {
  const float* x  = (const float*)d_in[0];
  const float* rr = (const float*)d_in[1];
  const float* th = (const float*)d_in[2];
  float* out = (float*)d_out;
  float* ws  = (float*)d_ws;

  size_t off = 0;
  auto alloc = [&](size_t n) {
    float* p = ws + off;
    off += (n + 63) & ~(size_t)63;
    return p;
  };
  float* D    = alloc((size_t)TT * KDIM);
  float* Lb   = alloc(16);
  float* mug  = alloc(NITER);
  float* xa   = alloc((size_t)PP * KPAD);   // transposed intermediate x
  if (off * sizeof(float) > ws_size) return;

  k_build_dic<<<(TT * KDIM + 255) / 256, 256, 0, stream>>>(rr, th, D, out + (size_t)KDIM * PP);
  k_prep<<<1, 1024, 0, stream>>>(D, Lb, mug);

  for (int r = 0; r < 3; ++r) {
    const int first = (r == 0), last = (r == 2);
    float* xo = last ? out : xa;
    k_round<<<PP, BT, 0, stream>>>(D, x, Lb, mug, xa, xo, first, last);
    if (!last) k_norm<<<1, 64, 0, stream>>>(Lb);
  }
}